// Round 2
// baseline (638.187 us; speedup 1.0000x reference)
//
#include <hip/hip_runtime.h>
#include <stdint.h>
#include <math.h>

#define FDIM 128
#define KDIM 384

struct Cols { int o25[25]; int i25[25]; int o10[10]; int i10[10]; };
struct ColsBoth { Cols c[2]; };

// ---------------- host-side reproduction of JAX threefry2x32 PRNG ----------------
// Matches modern JAX with jax_threefry_partitionable=True (default since 0.4.36+):
//   split(key, n)[i]        = E(key, (0, i))  -> both output words are the new key
//   random_bits(key,32,(m,))[i] = E0(key,(0,i)) ^ E1(key,(0,i))
static inline uint32_t rotl32(uint32_t x, uint32_t r){ return (x<<r)|(x>>(32u-r)); }

static void tf2x32(uint32_t k0, uint32_t k1, uint32_t c0, uint32_t c1,
                   uint32_t& o0, uint32_t& o1){
  const uint32_t ra[4] = {13u,15u,26u,6u};
  const uint32_t rb[4] = {17u,29u,16u,24u};
  uint32_t ks2 = k0 ^ k1 ^ 0x1BD11BDAu;
  uint32_t x0 = c0 + k0, x1 = c1 + k1;
  for(int i=0;i<4;i++){ x0 += x1; x1 = rotl32(x1, ra[i]); x1 ^= x0; }
  x0 += k1; x1 += ks2 + 1u;
  for(int i=0;i<4;i++){ x0 += x1; x1 = rotl32(x1, rb[i]); x1 ^= x0; }
  x0 += ks2; x1 += k0 + 2u;
  for(int i=0;i<4;i++){ x0 += x1; x1 = rotl32(x1, ra[i]); x1 ^= x0; }
  x0 += k0; x1 += k1 + 3u;
  for(int i=0;i<4;i++){ x0 += x1; x1 = rotl32(x1, rb[i]); x1 ^= x0; }
  x0 += k1; x1 += ks2 + 4u;
  for(int i=0;i<4;i++){ x0 += x1; x1 = rotl32(x1, ra[i]); x1 ^= x0; }
  x0 += ks2; x1 += k0 + 5u;
  o0 = x0; o1 = x1;
}

// split_foldlike: child key i of (ka,kb)
static void jax_split_child(uint32_t ka, uint32_t kb, uint32_t i,
                            uint32_t& oa, uint32_t& ob){
  tf2x32(ka, kb, 0u, i, oa, ob);
}

// partitionable random_bits (32-bit): bits[i] = xor of cipher words at counter (0,i)
static uint32_t jax_bits32(uint32_t ka, uint32_t kb, uint32_t i){
  uint32_t a,b; tf2x32(ka, kb, 0u, i, a, b);
  return a ^ b;
}

// jax.random.permutation(key, 64): one sort round (ceil(3*ln64/ln 2^32)=1).
// key,sub = split(key,2); bits = random_bits(sub,32,(64,)); stable-sort arange by bits asc.
static void jax_perm64(uint32_t ka, uint32_t kb, int* perm){
  uint32_t sa, sb; jax_split_child(ka, kb, 1u, sa, sb);   // subkey = child 1
  uint32_t b[64]; int v[64];
  for(int i=0;i<64;i++){ b[i]=jax_bits32(sa, sb, (uint32_t)i); v[i]=i; }
  for(int i=1;i<64;i++){                                  // stable insertion sort
    uint32_t bb=b[i]; int vv=v[i]; int j=i-1;
    while(j>=0 && b[j]>bb){ b[j+1]=b[j]; v[j+1]=v[j]; j--; }
    b[j+1]=bb; v[j+1]=vv;
  }
  for(int i=0;i<64;i++) perm[i]=v[i];
}

static void compute_cols(ColsBoth& cb){
  // root typed key jax.random.key(42) -> data (0,42); k1,k2 = split(root)
  uint32_t k1a,k1b,k2a,k2b;
  jax_split_child(0u, 42u, 0u, k1a, k1b);
  jax_split_child(0u, 42u, 1u, k2a, k2b);
  for(int side=0; side<2; side++){
    uint32_t ka = side ? k2a : k1a;
    uint32_t kb = side ? k2b : k1b;
    // _sample k=0 (t=1, n=25): key,c1,c2 = split(key,3) -> children 0,1,2
    uint32_t nka,nkb, c1a,c1b, c2a,c2b;
    jax_split_child(ka,kb,0u,nka,nkb);
    jax_split_child(ka,kb,1u,c1a,c1b);
    jax_split_child(ka,kb,2u,c2a,c2b);
    int p[64];
    jax_perm64(c1a,c1b,p); for(int i=0;i<25;i++) cb.c[side].o25[i]=p[i];
    jax_perm64(c2a,c2b,p); for(int i=0;i<25;i++) cb.c[side].i25[i]=p[i];
    // k=1 (t=0, n=10)
    uint32_t d1a,d1b,d2a,d2b, xka,xkb;
    jax_split_child(nka,nkb,0u,xka,xkb); (void)xka; (void)xkb;
    jax_split_child(nka,nkb,1u,d1a,d1b);
    jax_split_child(nka,nkb,2u,d2a,d2b);
    jax_perm64(d1a,d1b,p); for(int i=0;i<10;i++) cb.c[side].o10[i]=p[i];
    jax_perm64(d2a,d2b,p); for(int i=0;i<10;i++) cb.c[side].i10[i]=p[i];
  }
}

// ---------------- device kernels ----------------

// Build s_hop1[2][256][50]: per node, 25 sampled out-neighbors then 25 in-neighbors.
__global__ __launch_bounds__(256) void sample1_kernel(
    const int* __restrict__ nodes1, const int* __restrict__ nodes2,
    const int* __restrict__ nout, const int* __restrict__ nin,
    int* __restrict__ s_hop1, ColsBoth cb){
  int idx = blockIdx.x*blockDim.x + threadIdx.x;    // 2*256*50 = 25600
  if(idx >= 2*256*50) return;
  int side = idx / (256*50);
  int rem  = idx % (256*50);
  int b = rem / 50, j = rem % 50;
  int node = (side ? nodes2 : nodes1)[b];
  const Cols& c = cb.c[side];
  int nbr = (j < 25) ? nout[(long)node*64 + c.o25[j]]
                     : nin [(long)node*64 + c.i25[j-25]];
  s_hop1[idx] = nbr;
}

// Build s_hop2[2][12800][20]: per hop1 node, 10 out then 10 in.
__global__ __launch_bounds__(256) void sample2_kernel(
    const int* __restrict__ s_hop1,
    const int* __restrict__ nout, const int* __restrict__ nin,
    int* __restrict__ s_hop2, ColsBoth cb){
  int idx = blockIdx.x*blockDim.x + threadIdx.x;    // 2*12800*20 = 512000
  if(idx >= 2*12800*20) return;
  int side = idx / (12800*20);
  int rem  = idx % (12800*20);
  int r = rem / 20, j = rem % 20;
  int node = s_hop1[side*12800 + r];
  const Cols& c = cb.c[side];
  int nbr = (j < 10) ? nout[(long)node*64 + c.o10[j]]
                     : nin [(long)node*64 + c.i10[j-10]];
  s_hop2[idx] = nbr;
}

// GraphConvolution on raw features: out[r] = sigmoid(concat(self, mean_out, mean_in) @ W)
// 16 rows/block, 256 threads: (rowgroup rg = tid>>4) x (lane = tid&15, 8 channels each)
__global__ __launch_bounds__(256) void gc_feat_kernel(
    const float* __restrict__ feat,     // [N][128]
    const int*  __restrict__ self_idx,  // [R]
    const int*  __restrict__ nbr_idx,   // [R][2n]
    int n, int R,
    const float* __restrict__ W,        // [384][128]
    float* __restrict__ out)            // [R][128]
{
  __shared__ float agg[16][385];        // +1 pad: stride%32==1 -> conflict-free
  int tid = threadIdx.x;
  int rg = tid >> 4, lane = tid & 15;
  int row = blockIdx.x * 16 + rg;
  int c0 = lane * 8;
  float inv_n = 1.0f / (float)n;

  if(row < R){
    // self
    const float* sp = feat + (long)self_idx[row]*FDIM + c0;
    float4 a0 = *(const float4*)sp;
    float4 a1 = *(const float4*)(sp+4);
    *(float4*)&agg[rg][c0]   = a0;
    *(float4*)&agg[rg][c0+4] = a1;
    // mean over out-neighbors [0..n) and in-neighbors [n..2n)
    const int* nb = nbr_idx + (long)row*2*n;
    float4 s0 = make_float4(0,0,0,0), s1 = make_float4(0,0,0,0);
    for(int j=0;j<n;j++){
      const float* fp = feat + (long)nb[j]*FDIM + c0;
      float4 x = *(const float4*)fp; float4 y = *(const float4*)(fp+4);
      s0.x+=x.x; s0.y+=x.y; s0.z+=x.z; s0.w+=x.w;
      s1.x+=y.x; s1.y+=y.y; s1.z+=y.z; s1.w+=y.w;
    }
    agg[rg][128+c0+0]=s0.x*inv_n; agg[rg][128+c0+1]=s0.y*inv_n;
    agg[rg][128+c0+2]=s0.z*inv_n; agg[rg][128+c0+3]=s0.w*inv_n;
    agg[rg][128+c0+4]=s1.x*inv_n; agg[rg][128+c0+5]=s1.y*inv_n;
    agg[rg][128+c0+6]=s1.z*inv_n; agg[rg][128+c0+7]=s1.w*inv_n;
    s0 = make_float4(0,0,0,0); s1 = make_float4(0,0,0,0);
    for(int j=n;j<2*n;j++){
      const float* fp = feat + (long)nb[j]*FDIM + c0;
      float4 x = *(const float4*)fp; float4 y = *(const float4*)(fp+4);
      s0.x+=x.x; s0.y+=x.y; s0.z+=x.z; s0.w+=x.w;
      s1.x+=y.x; s1.y+=y.y; s1.z+=y.z; s1.w+=y.w;
    }
    agg[rg][256+c0+0]=s0.x*inv_n; agg[rg][256+c0+1]=s0.y*inv_n;
    agg[rg][256+c0+2]=s0.z*inv_n; agg[rg][256+c0+3]=s0.w*inv_n;
    agg[rg][256+c0+4]=s1.x*inv_n; agg[rg][256+c0+5]=s1.y*inv_n;
    agg[rg][256+c0+6]=s1.z*inv_n; agg[rg][256+c0+7]=s1.w*inv_n;
  }
  __syncthreads();

  if(row < R){
    float acc[8] = {0,0,0,0,0,0,0,0};
    #pragma unroll 4
    for(int k=0;k<KDIM;k++){
      float a = agg[rg][k];
      const float* wr = W + (long)k*FDIM + c0;
      float4 w0 = *(const float4*)wr; float4 w1 = *(const float4*)(wr+4);
      acc[0]+=a*w0.x; acc[1]+=a*w0.y; acc[2]+=a*w0.z; acc[3]+=a*w0.w;
      acc[4]+=a*w1.x; acc[5]+=a*w1.y; acc[6]+=a*w1.z; acc[7]+=a*w1.w;
    }
    float4 o0, o1;
    o0.x = 1.0f/(1.0f+expf(-acc[0])); o0.y = 1.0f/(1.0f+expf(-acc[1]));
    o0.z = 1.0f/(1.0f+expf(-acc[2])); o0.w = 1.0f/(1.0f+expf(-acc[3]));
    o1.x = 1.0f/(1.0f+expf(-acc[4])); o1.y = 1.0f/(1.0f+expf(-acc[5]));
    o1.z = 1.0f/(1.0f+expf(-acc[6])); o1.w = 1.0f/(1.0f+expf(-acc[7]));
    float* op = out + (long)row*FDIM + c0;
    *(float4*)op = o0; *(float4*)(op+4) = o1;
  }
}

// Layer-1: agg over h1 (25 out + 25 in by position), head GEMM+sigmoid, final projection.
// grid: ((side*3+head)*16 + tile), 96 blocks.
__global__ __launch_bounds__(256) void head_kernel(
    const float* __restrict__ h0,   // [2][256][128]
    const float* __restrict__ h1,   // [2][12800][128]
    const float* __restrict__ Wm, const float* __restrict__ Ws, const float* __restrict__ Wp,
    const float* __restrict__ Dm, const float* __restrict__ Ds, const float* __restrict__ Dp,
    float* __restrict__ out)        // [6][256][64]
{
  __shared__ float agg[16][385];
  __shared__ float hb[16][129];
  int bid = blockIdx.x;
  int tile = bid & 15;
  int sh = bid >> 4;              // 0..5
  int side = sh / 3, head = sh % 3;
  int tid = threadIdx.x;
  int rg = tid >> 4, lane = tid & 15;
  int b = tile*16 + rg;
  int c0 = lane * 8;
  const float inv25 = 1.0f/25.0f;

  {
    const float* sp = h0 + ((long)side*256 + b)*FDIM + c0;
    float4 a0 = *(const float4*)sp; float4 a1 = *(const float4*)(sp+4);
    *(float4*)&agg[rg][c0] = a0; *(float4*)&agg[rg][c0+4] = a1;
    const float* base = h1 + ((long)side*12800 + (long)b*50)*FDIM + c0;
    float4 s0 = make_float4(0,0,0,0), s1 = make_float4(0,0,0,0);
    for(int j=0;j<25;j++){
      const float* fp = base + (long)j*FDIM;
      float4 x = *(const float4*)fp; float4 y = *(const float4*)(fp+4);
      s0.x+=x.x; s0.y+=x.y; s0.z+=x.z; s0.w+=x.w;
      s1.x+=y.x; s1.y+=y.y; s1.z+=y.z; s1.w+=y.w;
    }
    agg[rg][128+c0+0]=s0.x*inv25; agg[rg][128+c0+1]=s0.y*inv25;
    agg[rg][128+c0+2]=s0.z*inv25; agg[rg][128+c0+3]=s0.w*inv25;
    agg[rg][128+c0+4]=s1.x*inv25; agg[rg][128+c0+5]=s1.y*inv25;
    agg[rg][128+c0+6]=s1.z*inv25; agg[rg][128+c0+7]=s1.w*inv25;
    s0 = make_float4(0,0,0,0); s1 = make_float4(0,0,0,0);
    for(int j=25;j<50;j++){
      const float* fp = base + (long)j*FDIM;
      float4 x = *(const float4*)fp; float4 y = *(const float4*)(fp+4);
      s0.x+=x.x; s0.y+=x.y; s0.z+=x.z; s0.w+=x.w;
      s1.x+=y.x; s1.y+=y.y; s1.z+=y.z; s1.w+=y.w;
    }
    agg[rg][256+c0+0]=s0.x*inv25; agg[rg][256+c0+1]=s0.y*inv25;
    agg[rg][256+c0+2]=s0.z*inv25; agg[rg][256+c0+3]=s0.w*inv25;
    agg[rg][256+c0+4]=s1.x*inv25; agg[rg][256+c0+5]=s1.y*inv25;
    agg[rg][256+c0+6]=s1.z*inv25; agg[rg][256+c0+7]=s1.w*inv25;
  }
  __syncthreads();

  const float* W = (head==0) ? Wm : (head==1) ? Ws : Wp;
  {
    float acc[8] = {0,0,0,0,0,0,0,0};
    #pragma unroll 4
    for(int k=0;k<KDIM;k++){
      float a = agg[rg][k];
      const float* wr = W + (long)k*FDIM + c0;
      float4 w0 = *(const float4*)wr; float4 w1 = *(const float4*)(wr+4);
      acc[0]+=a*w0.x; acc[1]+=a*w0.y; acc[2]+=a*w0.z; acc[3]+=a*w0.w;
      acc[4]+=a*w1.x; acc[5]+=a*w1.y; acc[6]+=a*w1.z; acc[7]+=a*w1.w;
    }
    #pragma unroll
    for(int i=0;i<8;i++) hb[rg][c0+i] = 1.0f/(1.0f+expf(-acc[i]));
  }
  __syncthreads();

  const float* D = (head==0) ? Dm : (head==1) ? Ds : Dp;
  {
    int cd = lane * 4;               // 16 lanes x 4 = 64 cols
    float a0=0,a1=0,a2=0,a3=0;
    #pragma unroll 4
    for(int k=0;k<FDIM;k++){
      float hv = hb[rg][k];
      const float* dr = D + (long)k*64 + cd;
      float4 d = *(const float4*)dr;
      a0 += hv*d.x; a1 += hv*d.y; a2 += hv*d.z; a3 += hv*d.w;
    }
    float* op = out + ((long)(side*3+head)*256 + b)*64 + cd;
    *(float4*)op = make_float4(a0,a1,a2,a3);
  }
}

// ---------------- launch ----------------
extern "C" void kernel_launch(void* const* d_in, const int* in_sizes, int n_in,
                              void* d_out, int out_size, void* d_ws, size_t ws_size,
                              hipStream_t stream) {
  const int*   nodes1  = (const int*)d_in[0];
  const int*   nodes2  = (const int*)d_in[1];
  const int*   nout    = (const int*)d_in[2];
  const int*   nin     = (const int*)d_in[3];
  const float* feat    = (const float*)d_in[4];
  const float* W_in    = (const float*)d_in[5];
  const float* W_mean  = (const float*)d_in[6];
  const float* W_std   = (const float*)d_in[7];
  const float* W_pi    = (const float*)d_in[8];
  const float* Wd_mean = (const float*)d_in[11];
  const float* Wd_std  = (const float*)d_in[12];
  const float* Wd_pi   = (const float*)d_in[13];
  float* out = (float*)d_out;

  // workspace layout
  int*   s_hop1 = (int*)d_ws;                    // [2][12800]
  int*   s_hop2 = s_hop1 + 2*12800;              // [2][256000]
  float* h0     = (float*)(s_hop2 + 2*256000);   // [2][256][128]
  float* h1     = h0 + 2*256*128;                // [2][12800][128]

  ColsBoth cb;
  compute_cols(cb);

  sample1_kernel<<<(2*256*50 + 255)/256, 256, 0, stream>>>(nodes1, nodes2, nout, nin, s_hop1, cb);
  sample2_kernel<<<(2*12800*20 + 255)/256, 256, 0, stream>>>(s_hop1, nout, nin, s_hop2, cb);

  // layer 0, hop 0 (n=25): self = nodes, neighbors = s_hop1 rows
  gc_feat_kernel<<<16, 256, 0, stream>>>(feat, nodes1, s_hop1,            25, 256,   W_in, h0);
  gc_feat_kernel<<<16, 256, 0, stream>>>(feat, nodes2, s_hop1 + 12800,    25, 256,   W_in, h0 + 256*128);
  // layer 0, hop 1 (n=10): self = s_hop1, neighbors = s_hop2 rows
  gc_feat_kernel<<<800, 256, 0, stream>>>(feat, s_hop1,         s_hop2,          10, 12800, W_in, h1);
  gc_feat_kernel<<<800, 256, 0, stream>>>(feat, s_hop1 + 12800, s_hop2 + 256000, 10, 12800, W_in, h1 + 12800*128);

  // layer 1 + heads + final projection
  head_kernel<<<96, 256, 0, stream>>>(h0, h1, W_mean, W_std, W_pi, Wd_mean, Wd_std, Wd_pi, out);
}

// Round 3
// 478.574 us; speedup vs baseline: 1.3335x; 1.3335x over previous
//
#include <hip/hip_runtime.h>
#include <stdint.h>
#include <math.h>

#define FDIM 128
#define KDIM 384

struct Cols { int o25[25]; int i25[25]; int o10[10]; int i10[10]; };
struct ColsBoth { Cols c[2]; };

// ---------------- host-side reproduction of JAX threefry2x32 PRNG ----------------
// Matches modern JAX with jax_threefry_partitionable=True (default since 0.4.36+):
//   split(key, n)[i]            = E(key, (0, i))  -> both output words are the new key
//   random_bits(key,32,(m,))[i] = E0(key,(0,i)) ^ E1(key,(0,i))
static inline uint32_t rotl32(uint32_t x, uint32_t r){ return (x<<r)|(x>>(32u-r)); }

static void tf2x32(uint32_t k0, uint32_t k1, uint32_t c0, uint32_t c1,
                   uint32_t& o0, uint32_t& o1){
  const uint32_t ra[4] = {13u,15u,26u,6u};
  const uint32_t rb[4] = {17u,29u,16u,24u};
  uint32_t ks2 = k0 ^ k1 ^ 0x1BD11BDAu;
  uint32_t x0 = c0 + k0, x1 = c1 + k1;
  for(int i=0;i<4;i++){ x0 += x1; x1 = rotl32(x1, ra[i]); x1 ^= x0; }
  x0 += k1; x1 += ks2 + 1u;
  for(int i=0;i<4;i++){ x0 += x1; x1 = rotl32(x1, rb[i]); x1 ^= x0; }
  x0 += ks2; x1 += k0 + 2u;
  for(int i=0;i<4;i++){ x0 += x1; x1 = rotl32(x1, ra[i]); x1 ^= x0; }
  x0 += k0; x1 += k1 + 3u;
  for(int i=0;i<4;i++){ x0 += x1; x1 = rotl32(x1, rb[i]); x1 ^= x0; }
  x0 += k1; x1 += ks2 + 4u;
  for(int i=0;i<4;i++){ x0 += x1; x1 = rotl32(x1, ra[i]); x1 ^= x0; }
  x0 += ks2; x1 += k0 + 5u;
  o0 = x0; o1 = x1;
}

static void jax_split_child(uint32_t ka, uint32_t kb, uint32_t i,
                            uint32_t& oa, uint32_t& ob){
  tf2x32(ka, kb, 0u, i, oa, ob);
}

static uint32_t jax_bits32(uint32_t ka, uint32_t kb, uint32_t i){
  uint32_t a,b; tf2x32(ka, kb, 0u, i, a, b);
  return a ^ b;
}

// jax.random.permutation(key, 64): one sort round.
static void jax_perm64(uint32_t ka, uint32_t kb, int* perm){
  uint32_t sa, sb; jax_split_child(ka, kb, 1u, sa, sb);   // subkey = child 1
  uint32_t b[64]; int v[64];
  for(int i=0;i<64;i++){ b[i]=jax_bits32(sa, sb, (uint32_t)i); v[i]=i; }
  for(int i=1;i<64;i++){                                  // stable insertion sort
    uint32_t bb=b[i]; int vv=v[i]; int j=i-1;
    while(j>=0 && b[j]>bb){ b[j+1]=b[j]; v[j+1]=v[j]; j--; }
    b[j+1]=bb; v[j+1]=vv;
  }
  for(int i=0;i<64;i++) perm[i]=v[i];
}

static void compute_cols(ColsBoth& cb){
  uint32_t k1a,k1b,k2a,k2b;
  jax_split_child(0u, 42u, 0u, k1a, k1b);
  jax_split_child(0u, 42u, 1u, k2a, k2b);
  for(int side=0; side<2; side++){
    uint32_t ka = side ? k2a : k1a;
    uint32_t kb = side ? k2b : k1b;
    uint32_t nka,nkb, c1a,c1b, c2a,c2b;
    jax_split_child(ka,kb,0u,nka,nkb);
    jax_split_child(ka,kb,1u,c1a,c1b);
    jax_split_child(ka,kb,2u,c2a,c2b);
    int p[64];
    jax_perm64(c1a,c1b,p); for(int i=0;i<25;i++) cb.c[side].o25[i]=p[i];
    jax_perm64(c2a,c2b,p); for(int i=0;i<25;i++) cb.c[side].i25[i]=p[i];
    uint32_t d1a,d1b,d2a,d2b;
    jax_split_child(nka,nkb,1u,d1a,d1b);
    jax_split_child(nka,nkb,2u,d2a,d2b);
    jax_perm64(d1a,d1b,p); for(int i=0;i<10;i++) cb.c[side].o10[i]=p[i];
    jax_perm64(d2a,d2b,p); for(int i=0;i<10;i++) cb.c[side].i10[i]=p[i];
  }
}

// ---------------- device helpers ----------------
__device__ __forceinline__ void acc8(const float* __restrict__ fp, float4& s0, float4& s1){
  float4 x = *(const float4*)fp; float4 y = *(const float4*)(fp+4);
  s0.x+=x.x; s0.y+=x.y; s0.z+=x.z; s0.w+=x.w;
  s1.x+=y.x; s1.y+=y.y; s1.z+=y.z; s1.w+=y.w;
}

// GEMM 384->128 + sigmoid from LDS agg row, write 8 channels per lane.
__device__ __forceinline__ void gemm_sig_store(
    const float (*agg)[388], int rg, int c0,
    const float* __restrict__ W, float* __restrict__ op){
  float acc[8] = {0,0,0,0,0,0,0,0};
  #pragma unroll 4
  for(int k=0;k<KDIM;k++){
    float a = agg[rg][k];
    const float* wr = W + (long)k*FDIM + c0;
    float4 w0 = *(const float4*)wr; float4 w1 = *(const float4*)(wr+4);
    acc[0]+=a*w0.x; acc[1]+=a*w0.y; acc[2]+=a*w0.z; acc[3]+=a*w0.w;
    acc[4]+=a*w1.x; acc[5]+=a*w1.y; acc[6]+=a*w1.z; acc[7]+=a*w1.w;
  }
  float4 o0, o1;
  o0.x = 1.0f/(1.0f+expf(-acc[0])); o0.y = 1.0f/(1.0f+expf(-acc[1]));
  o0.z = 1.0f/(1.0f+expf(-acc[2])); o0.w = 1.0f/(1.0f+expf(-acc[3]));
  o1.x = 1.0f/(1.0f+expf(-acc[4])); o1.y = 1.0f/(1.0f+expf(-acc[5]));
  o1.z = 1.0f/(1.0f+expf(-acc[6])); o1.w = 1.0f/(1.0f+expf(-acc[7]));
  *(float4*)op = o0; *(float4*)(op+4) = o1;
}

// ---------------- device kernels ----------------

// s_hop1[2][256][50]: per root node, 25 sampled out-neighbors then 25 in.
__global__ __launch_bounds__(256) void sample1_kernel(
    const int* __restrict__ nodes1, const int* __restrict__ nodes2,
    const int* __restrict__ nout, const int* __restrict__ nin,
    int* __restrict__ s_hop1, ColsBoth cb){
  int idx = blockIdx.x*blockDim.x + threadIdx.x;    // 2*256*50 = 25600
  if(idx >= 2*256*50) return;
  int side = idx / (256*50);
  int rem  = idx % (256*50);
  int b = rem / 50, j = rem % 50;
  int node = (side ? nodes2 : nodes1)[b];
  const Cols& c = cb.c[side];
  int nbr = (j < 25) ? nout[(long)node*64 + c.o25[j]]
                     : nin [(long)node*64 + c.i25[j-25]];
  s_hop1[idx] = nbr;
}

// Hop-0 GC, both sides in one launch: 32 blocks x 16 rows. N=25 unrolled.
__global__ __launch_bounds__(256) void gc_hop0_kernel(
    const float* __restrict__ feat,
    const int* __restrict__ nodes1, const int* __restrict__ nodes2,
    const int* __restrict__ s_hop1,   // neighbor lists [512][50]
    const float* __restrict__ W, float* __restrict__ h0)
{
  __shared__ float agg[16][388];
  int tid = threadIdx.x, rg = tid>>4, lane = tid&15;
  int row = blockIdx.x*16 + rg;       // 0..511 ; side = row>>8
  int side = row >> 8, b = row & 255;
  int c0 = lane*8;
  int self = (side ? nodes2 : nodes1)[b];
  const int* nb = s_hop1 + row*50;

  {
    const float* sp = feat + (long)self*FDIM + c0;
    *(float4*)&agg[rg][c0]   = *(const float4*)sp;
    *(float4*)&agg[rg][c0+4] = *(const float4*)(sp+4);
  }
  const float inv = 1.0f/25.0f;
  float4 s0 = make_float4(0,0,0,0), s1 = make_float4(0,0,0,0);
  #pragma unroll
  for(int j=0;j<25;j++) acc8(feat + (long)nb[j]*FDIM + c0, s0, s1);
  *(float4*)&agg[rg][128+c0]   = make_float4(s0.x*inv,s0.y*inv,s0.z*inv,s0.w*inv);
  *(float4*)&agg[rg][128+c0+4] = make_float4(s1.x*inv,s1.y*inv,s1.z*inv,s1.w*inv);
  s0 = make_float4(0,0,0,0); s1 = make_float4(0,0,0,0);
  #pragma unroll
  for(int j=25;j<50;j++) acc8(feat + (long)nb[j]*FDIM + c0, s0, s1);
  *(float4*)&agg[rg][256+c0]   = make_float4(s0.x*inv,s0.y*inv,s0.z*inv,s0.w*inv);
  *(float4*)&agg[rg][256+c0+4] = make_float4(s1.x*inv,s1.y*inv,s1.z*inv,s1.w*inv);
  __syncthreads();

  gemm_sig_store(agg, rg, c0, W, h0 + (long)row*FDIM + c0);
}

// Hop-1 GC, both sides, sample2 fused inline: 1600 blocks x 16 rows. N=10 unrolled.
__global__ __launch_bounds__(256) void gc_hop1_kernel(
    const float* __restrict__ feat, const int* __restrict__ s_hop1,
    const int* __restrict__ nout, const int* __restrict__ nin,
    const float* __restrict__ W, float* __restrict__ h1, ColsBoth cb)
{
  __shared__ float agg[16][388];
  int tid = threadIdx.x, rg = tid>>4, lane = tid&15;
  int row = blockIdx.x*16 + rg;       // 0..25599
  int side = (row >= 12800) ? 1 : 0;  // wave-uniform (12800 % 16 == 0)
  int c0 = lane*8;
  int node = s_hop1[row];
  const long nb = (long)node*64;
  const Cols& c = cb.c[side];

  {
    const float* sp = feat + (long)node*FDIM + c0;
    *(float4*)&agg[rg][c0]   = *(const float4*)sp;
    *(float4*)&agg[rg][c0+4] = *(const float4*)(sp+4);
  }
  const float inv = 0.1f;
  float4 s0 = make_float4(0,0,0,0), s1 = make_float4(0,0,0,0);
  #pragma unroll
  for(int j=0;j<10;j++){
    int idx = nout[nb + c.o10[j]];
    acc8(feat + (long)idx*FDIM + c0, s0, s1);
  }
  *(float4*)&agg[rg][128+c0]   = make_float4(s0.x*inv,s0.y*inv,s0.z*inv,s0.w*inv);
  *(float4*)&agg[rg][128+c0+4] = make_float4(s1.x*inv,s1.y*inv,s1.z*inv,s1.w*inv);
  s0 = make_float4(0,0,0,0); s1 = make_float4(0,0,0,0);
  #pragma unroll
  for(int j=0;j<10;j++){
    int idx = nin[nb + c.i10[j]];
    acc8(feat + (long)idx*FDIM + c0, s0, s1);
  }
  *(float4*)&agg[rg][256+c0]   = make_float4(s0.x*inv,s0.y*inv,s0.z*inv,s0.w*inv);
  *(float4*)&agg[rg][256+c0+4] = make_float4(s1.x*inv,s1.y*inv,s1.z*inv,s1.w*inv);
  __syncthreads();

  gemm_sig_store(agg, rg, c0, W, h1 + (long)row*FDIM + c0);
}

// Layer-1 aggregation: one row per block (512 blocks), parallel over neighbors.
// agg2[row][384] = [h0_self | mean(h1 out 25) | mean(h1 in 25)]
__global__ __launch_bounds__(256) void agg1_kernel(
    const float* __restrict__ h0, const float* __restrict__ h1,
    float* __restrict__ agg2)
{
  int row = blockIdx.x;               // 0..511 (side*256 + b)
  int t = threadIdx.x;
  int ch = t & 127;
  int half = t >> 7;                  // 0: out (j 0..24), 1: in (j 25..49)
  const float* base = h1 + (long)row*50*FDIM + half*25*FDIM + ch;
  float s = 0.f;
  #pragma unroll
  for(int j=0;j<25;j++) s += base[j*FDIM];
  agg2[(long)row*KDIM + 128 + half*128 + ch] = s * (1.0f/25.0f);
  if(half == 0) agg2[(long)row*KDIM + ch] = h0[(long)row*FDIM + ch];
}

// Heads: GEMM 384->128 + sigmoid, then 128->64 projection. 96 blocks.
__global__ __launch_bounds__(256) void head2_kernel(
    const float* __restrict__ agg2,
    const float* __restrict__ Wm, const float* __restrict__ Ws, const float* __restrict__ Wp,
    const float* __restrict__ Dm, const float* __restrict__ Ds, const float* __restrict__ Dp,
    float* __restrict__ out)            // [6][256][64]
{
  __shared__ float agg[16][388];
  __shared__ float hb[16][129];
  int bid = blockIdx.x;
  int tile = bid & 15;
  int sh = bid >> 4;                  // 0..5
  int side = sh / 3, head = sh % 3;
  int tid = threadIdx.x, rg = tid>>4, lane = tid&15;
  int b = tile*16 + rg;
  int arow = side*256 + b;
  int c0 = lane*8;

  // stage agg2 row into LDS (16 lanes x 24 floats each)
  {
    const float* ar = agg2 + (long)arow*KDIM;
    #pragma unroll
    for(int i=0;i<6;i++){
      *(float4*)&agg[rg][lane*24 + i*4] = *(const float4*)(ar + lane*24 + i*4);
    }
  }
  __syncthreads();

  const float* W = (head==0) ? Wm : (head==1) ? Ws : Wp;
  {
    float acc[8] = {0,0,0,0,0,0,0,0};
    #pragma unroll 4
    for(int k=0;k<KDIM;k++){
      float a = agg[rg][k];
      const float* wr = W + (long)k*FDIM + c0;
      float4 w0 = *(const float4*)wr; float4 w1 = *(const float4*)(wr+4);
      acc[0]+=a*w0.x; acc[1]+=a*w0.y; acc[2]+=a*w0.z; acc[3]+=a*w0.w;
      acc[4]+=a*w1.x; acc[5]+=a*w1.y; acc[6]+=a*w1.z; acc[7]+=a*w1.w;
    }
    #pragma unroll
    for(int i=0;i<8;i++) hb[rg][c0+i] = 1.0f/(1.0f+expf(-acc[i]));
  }
  __syncthreads();

  const float* D = (head==0) ? Dm : (head==1) ? Ds : Dp;
  {
    int cd = lane * 4;                // 16 lanes x 4 = 64 cols
    float a0=0,a1=0,a2=0,a3=0;
    #pragma unroll 4
    for(int k=0;k<FDIM;k++){
      float hv = hb[rg][k];
      const float* dr = D + (long)k*64 + cd;
      float4 d = *(const float4*)dr;
      a0 += hv*d.x; a1 += hv*d.y; a2 += hv*d.z; a3 += hv*d.w;
    }
    float* op = out + ((long)(side*3+head)*256 + b)*64 + cd;
    *(float4*)op = make_float4(a0,a1,a2,a3);
  }
}

// ---------------- launch ----------------
extern "C" void kernel_launch(void* const* d_in, const int* in_sizes, int n_in,
                              void* d_out, int out_size, void* d_ws, size_t ws_size,
                              hipStream_t stream) {
  const int*   nodes1  = (const int*)d_in[0];
  const int*   nodes2  = (const int*)d_in[1];
  const int*   nout    = (const int*)d_in[2];
  const int*   nin     = (const int*)d_in[3];
  const float* feat    = (const float*)d_in[4];
  const float* W_in    = (const float*)d_in[5];
  const float* W_mean  = (const float*)d_in[6];
  const float* W_std   = (const float*)d_in[7];
  const float* W_pi    = (const float*)d_in[8];
  const float* Wd_mean = (const float*)d_in[11];
  const float* Wd_std  = (const float*)d_in[12];
  const float* Wd_pi   = (const float*)d_in[13];
  float* out = (float*)d_out;

  // workspace layout
  int*   s_hop1 = (int*)d_ws;                    // [2][256][50] = 25600 ints
  float* h0     = (float*)(s_hop1 + 2*12800);    // [2][256][128]
  float* h1     = h0 + 2*256*128;                // [2][12800][128]
  float* agg2   = h1 + 2*12800*128;              // [2][256][384]

  ColsBoth cb;
  compute_cols(cb);

  sample1_kernel<<<(2*256*50 + 255)/256, 256, 0, stream>>>(nodes1, nodes2, nout, nin, s_hop1, cb);
  gc_hop1_kernel<<<1600, 256, 0, stream>>>(feat, s_hop1, nout, nin, W_in, h1, cb);
  gc_hop0_kernel<<<32, 256, 0, stream>>>(feat, nodes1, nodes2, s_hop1, W_in, h0);
  agg1_kernel<<<512, 256, 0, stream>>>(h0, h1, agg2);
  head2_kernel<<<96, 256, 0, stream>>>(agg2, W_mean, W_std, W_pi, Wd_mean, Wd_std, Wd_pi, out);
}

// Round 4
// 333.580 us; speedup vs baseline: 1.9131x; 1.4347x over previous
//
#include <hip/hip_runtime.h>
#include <stdint.h>
#include <math.h>

#define FDIM 128
#define KDIM 384
#define NROWS 26112   // 512 hop0 rows + 25600 hop1 rows

struct Cols { int o25[25]; int i25[25]; int o10[10]; int i10[10]; };
struct ColsBoth { Cols c[2]; };

// ---------------- host-side JAX threefry (partitionable=True) ----------------
static inline uint32_t rotl32(uint32_t x, uint32_t r){ return (x<<r)|(x>>(32u-r)); }

static void tf2x32(uint32_t k0, uint32_t k1, uint32_t c0, uint32_t c1,
                   uint32_t& o0, uint32_t& o1){
  const uint32_t ra[4] = {13u,15u,26u,6u};
  const uint32_t rb[4] = {17u,29u,16u,24u};
  uint32_t ks2 = k0 ^ k1 ^ 0x1BD11BDAu;
  uint32_t x0 = c0 + k0, x1 = c1 + k1;
  for(int i=0;i<4;i++){ x0 += x1; x1 = rotl32(x1, ra[i]); x1 ^= x0; }
  x0 += k1; x1 += ks2 + 1u;
  for(int i=0;i<4;i++){ x0 += x1; x1 = rotl32(x1, rb[i]); x1 ^= x0; }
  x0 += ks2; x1 += k0 + 2u;
  for(int i=0;i<4;i++){ x0 += x1; x1 = rotl32(x1, ra[i]); x1 ^= x0; }
  x0 += k0; x1 += k1 + 3u;
  for(int i=0;i<4;i++){ x0 += x1; x1 = rotl32(x1, rb[i]); x1 ^= x0; }
  x0 += k1; x1 += ks2 + 4u;
  for(int i=0;i<4;i++){ x0 += x1; x1 = rotl32(x1, ra[i]); x1 ^= x0; }
  x0 += ks2; x1 += k0 + 5u;
  o0 = x0; o1 = x1;
}

static void jax_split_child(uint32_t ka, uint32_t kb, uint32_t i,
                            uint32_t& oa, uint32_t& ob){
  tf2x32(ka, kb, 0u, i, oa, ob);
}

static uint32_t jax_bits32(uint32_t ka, uint32_t kb, uint32_t i){
  uint32_t a,b; tf2x32(ka, kb, 0u, i, a, b);
  return a ^ b;
}

static void jax_perm64(uint32_t ka, uint32_t kb, int* perm){
  uint32_t sa, sb; jax_split_child(ka, kb, 1u, sa, sb);
  uint32_t b[64]; int v[64];
  for(int i=0;i<64;i++){ b[i]=jax_bits32(sa, sb, (uint32_t)i); v[i]=i; }
  for(int i=1;i<64;i++){
    uint32_t bb=b[i]; int vv=v[i]; int j=i-1;
    while(j>=0 && b[j]>bb){ b[j+1]=b[j]; v[j+1]=v[j]; j--; }
    b[j+1]=bb; v[j+1]=vv;
  }
  for(int i=0;i<64;i++) perm[i]=v[i];
}

static void compute_cols(ColsBoth& cb){
  uint32_t k1a,k1b,k2a,k2b;
  jax_split_child(0u, 42u, 0u, k1a, k1b);
  jax_split_child(0u, 42u, 1u, k2a, k2b);
  for(int side=0; side<2; side++){
    uint32_t ka = side ? k2a : k1a;
    uint32_t kb = side ? k2b : k1b;
    uint32_t nka,nkb, c1a,c1b, c2a,c2b;
    jax_split_child(ka,kb,0u,nka,nkb);
    jax_split_child(ka,kb,1u,c1a,c1b);
    jax_split_child(ka,kb,2u,c2a,c2b);
    int p[64];
    jax_perm64(c1a,c1b,p); for(int i=0;i<25;i++) cb.c[side].o25[i]=p[i];
    jax_perm64(c2a,c2b,p); for(int i=0;i<25;i++) cb.c[side].i25[i]=p[i];
    uint32_t d1a,d1b,d2a,d2b;
    jax_split_child(nka,nkb,1u,d1a,d1b);
    jax_split_child(nka,nkb,2u,d2a,d2b);
    jax_perm64(d1a,d1b,p); for(int i=0;i<10;i++) cb.c[side].o10[i]=p[i];
    jax_perm64(d2a,d2b,p); for(int i=0;i<10;i++) cb.c[side].i10[i]=p[i];
  }
}

// ---------------- device helpers ----------------
__device__ __forceinline__ float getc(const float4& v, int i){
  return (i==0)?v.x:(i==1)?v.y:(i==2)?v.z:v.w;
}
__device__ __forceinline__ float sigf(float x){ return 1.0f/(1.0f+expf(-x)); }
__device__ __forceinline__ void add4(float4& s, const float4& v){
  s.x+=v.x; s.y+=v.y; s.z+=v.z; s.w+=v.w;
}

// ---------------- kernels ----------------

// s_hop1[2][256][50]: per root node, 25 sampled out-neighbors then 25 in.
__global__ __launch_bounds__(256) void sample1_kernel(
    const int* __restrict__ nodes1, const int* __restrict__ nodes2,
    const int* __restrict__ nout, const int* __restrict__ nin,
    int* __restrict__ s_hop1, ColsBoth cb){
  int idx = blockIdx.x*blockDim.x + threadIdx.x;    // 25600
  if(idx >= 2*256*50) return;
  int side = idx / (256*50);
  int rem  = idx % (256*50);
  int b = rem / 50, j = rem % 50;
  int node = (side ? nodes2 : nodes1)[b];
  const Cols& c = cb.c[side];
  int nbr = (j < 25) ? nout[(long)node*64 + c.o25[j]]
                     : nin [(long)node*64 + c.i25[j-25]];
  s_hop1[idx] = nbr;
}

// Gather + mean-aggregate: one row per 32 lanes (lane covers 4 channels).
// Rows [0,512): hop0 (n=25, neighbors from s_hop1 lists, self from root nodes).
// Rows [512,26112): hop1 (n=10, sample2 computed inline). Writes agg[row_local][384].
__global__ __launch_bounds__(256) void gather_kernel(
    const float* __restrict__ feat,
    const int* __restrict__ nodes1, const int* __restrict__ nodes2,
    const int* __restrict__ s_hop1,
    const int* __restrict__ nout, const int* __restrict__ nin,
    float* __restrict__ agg, int base_row, ColsBoth cb)
{
  int t = threadIdx.x;
  int row_local = blockIdx.x*8 + (t>>5);
  int lane = t & 31;
  int c0 = lane*4;
  int row = base_row + row_local;

  float4 selfv, so, si;

  if(row < 512){                       // hop0: whole 8-row block uniform
    int side = row >> 8, b = row & 255;
    int node = (side ? nodes2 : nodes1)[b];
    selfv = *(const float4*)(feat + (long)node*FDIM + c0);
    const int* nb = s_hop1 + row*50;
    float4 acc = make_float4(0,0,0,0);
    #pragma unroll
    for(int jj=0; jj<25; jj+=5){
      int id[5]; float4 v[5];
      #pragma unroll
      for(int i=0;i<5;i++) id[i] = nb[jj+i];
      #pragma unroll
      for(int i=0;i<5;i++) v[i] = *(const float4*)(feat + (long)id[i]*FDIM + c0);
      #pragma unroll
      for(int i=0;i<5;i++) add4(acc, v[i]);
    }
    so = make_float4(acc.x/25.f, acc.y/25.f, acc.z/25.f, acc.w/25.f);
    acc = make_float4(0,0,0,0);
    #pragma unroll
    for(int jj=25; jj<50; jj+=5){
      int id[5]; float4 v[5];
      #pragma unroll
      for(int i=0;i<5;i++) id[i] = nb[jj+i];
      #pragma unroll
      for(int i=0;i<5;i++) v[i] = *(const float4*)(feat + (long)id[i]*FDIM + c0);
      #pragma unroll
      for(int i=0;i<5;i++) add4(acc, v[i]);
    }
    si = make_float4(acc.x/25.f, acc.y/25.f, acc.z/25.f, acc.w/25.f);
  } else {                             // hop1
    int hrow = row - 512;
    int side = (hrow >= 12800) ? 1 : 0;
    int node = s_hop1[hrow];
    const Cols& c = cb.c[side];
    const long nb = (long)node*64;
    int oid[10], iid[10];
    #pragma unroll
    for(int j=0;j<10;j++) oid[j] = nout[nb + c.o10[j]];
    #pragma unroll
    for(int j=0;j<10;j++) iid[j] = nin[nb + c.i10[j]];
    selfv = *(const float4*)(feat + (long)node*FDIM + c0);
    float4 v[10];
    #pragma unroll
    for(int j=0;j<10;j++) v[j] = *(const float4*)(feat + (long)oid[j]*FDIM + c0);
    float4 acc = make_float4(0,0,0,0);
    #pragma unroll
    for(int j=0;j<10;j++) add4(acc, v[j]);
    so = make_float4(acc.x*0.1f, acc.y*0.1f, acc.z*0.1f, acc.w*0.1f);
    #pragma unroll
    for(int j=0;j<10;j++) v[j] = *(const float4*)(feat + (long)iid[j]*FDIM + c0);
    acc = make_float4(0,0,0,0);
    #pragma unroll
    for(int j=0;j<10;j++) add4(acc, v[j]);
    si = make_float4(acc.x*0.1f, acc.y*0.1f, acc.z*0.1f, acc.w*0.1f);
  }

  float* ar = agg + (long)row_local*KDIM;
  *(float4*)(ar + c0)       = selfv;
  *(float4*)(ar + 128 + c0) = so;
  *(float4*)(ar + 256 + c0) = si;
}

// Blocked GEMM + sigmoid: out[r][128] = sig(A[r][384] @ W[384][128]).
// 64 rows/block, W staged in LDS in 4 chunks of 96 k; thread = 4 rows x 8 cols.
__global__ __launch_bounds__(256) void gemm_sig_kernel(
    const float* __restrict__ A, const float* __restrict__ W,
    float* __restrict__ out)
{
  __shared__ float Wbuf[96*128];       // 48 KB
  int t = threadIdx.x, lane = t&15, rg = t>>4;
  int r0 = blockIdx.x*64 + rg*4;
  int c0 = lane*8;
  float acc[4][8];
  #pragma unroll
  for(int r=0;r<4;r++)
    #pragma unroll
    for(int i=0;i<8;i++) acc[r][i]=0.f;

  for(int kc=0; kc<4; kc++){
    __syncthreads();
    const float4* ws = (const float4*)(W + kc*96*128);
    float4* wd = (float4*)Wbuf;
    #pragma unroll
    for(int i=0;i<12;i++) wd[i*256+t] = ws[i*256+t];
    __syncthreads();
    const float* Ab = A + (long)r0*KDIM + kc*96;
    #pragma unroll 2
    for(int k4=0;k4<96;k4+=4){
      float4 a0 = *(const float4*)(Ab + 0*KDIM + k4);
      float4 a1 = *(const float4*)(Ab + 1*KDIM + k4);
      float4 a2 = *(const float4*)(Ab + 2*KDIM + k4);
      float4 a3 = *(const float4*)(Ab + 3*KDIM + k4);
      #pragma unroll
      for(int kk=0;kk<4;kk++){
        float av0=getc(a0,kk), av1=getc(a1,kk), av2=getc(a2,kk), av3=getc(a3,kk);
        const float* wr = Wbuf + (k4+kk)*128 + c0;
        float4 w0 = *(const float4*)wr;
        float4 w1 = *(const float4*)(wr+4);
        acc[0][0]+=av0*w0.x; acc[0][1]+=av0*w0.y; acc[0][2]+=av0*w0.z; acc[0][3]+=av0*w0.w;
        acc[0][4]+=av0*w1.x; acc[0][5]+=av0*w1.y; acc[0][6]+=av0*w1.z; acc[0][7]+=av0*w1.w;
        acc[1][0]+=av1*w0.x; acc[1][1]+=av1*w0.y; acc[1][2]+=av1*w0.z; acc[1][3]+=av1*w0.w;
        acc[1][4]+=av1*w1.x; acc[1][5]+=av1*w1.y; acc[1][6]+=av1*w1.z; acc[1][7]+=av1*w1.w;
        acc[2][0]+=av2*w0.x; acc[2][1]+=av2*w0.y; acc[2][2]+=av2*w0.z; acc[2][3]+=av2*w0.w;
        acc[2][4]+=av2*w1.x; acc[2][5]+=av2*w1.y; acc[2][6]+=av2*w1.z; acc[2][7]+=av2*w1.w;
        acc[3][0]+=av3*w0.x; acc[3][1]+=av3*w0.y; acc[3][2]+=av3*w0.z; acc[3][3]+=av3*w0.w;
        acc[3][4]+=av3*w1.x; acc[3][5]+=av3*w1.y; acc[3][6]+=av3*w1.z; acc[3][7]+=av3*w1.w;
      }
    }
  }
  #pragma unroll
  for(int r=0;r<4;r++){
    float4 o0, o1;
    o0.x=sigf(acc[r][0]); o0.y=sigf(acc[r][1]); o0.z=sigf(acc[r][2]); o0.w=sigf(acc[r][3]);
    o1.x=sigf(acc[r][4]); o1.y=sigf(acc[r][5]); o1.z=sigf(acc[r][6]); o1.w=sigf(acc[r][7]);
    float* op = out + (long)(r0+r)*FDIM + c0;
    *(float4*)op = o0; *(float4*)(op+4) = o1;
  }
}

// Layer-1 aggregation: agg2[row][384] = [h0_self | mean(h1 out 25) | mean(h1 in 25)]
__global__ __launch_bounds__(256) void agg1_kernel(
    const float* __restrict__ h0, const float* __restrict__ h1,
    float* __restrict__ agg2)
{
  int row = blockIdx.x;               // 0..511
  int t = threadIdx.x;
  int ch = t & 127;
  int half = t >> 7;
  const float* base = h1 + (long)row*50*FDIM + half*25*FDIM + ch;
  float s = 0.f;
  #pragma unroll
  for(int j=0;j<25;j++) s += base[j*FDIM];
  agg2[(long)row*KDIM + 128 + half*128 + ch] = s * (1.0f/25.0f);
  if(half == 0) agg2[(long)row*KDIM + ch] = h0[(long)row*FDIM + ch];
}

// Heads: blocked GEMM 384->128 + sigmoid (W LDS-staged) + fused 128->64 projection.
// grid 24: head = blockIdx>>3, 64-row tile = blockIdx&7.
__global__ __launch_bounds__(256) void head_kernel(
    const float* __restrict__ agg2,
    const float* __restrict__ Wm, const float* __restrict__ Ws, const float* __restrict__ Wp,
    const float* __restrict__ Dm, const float* __restrict__ Ds, const float* __restrict__ Dp,
    float* __restrict__ out)            // [6][256][64]
{
  __shared__ float Wbuf[96*128];        // 48 KB (reused for D)
  __shared__ float hb[64*133];          // 34 KB, stride 133 breaks bank collisions
  int t = threadIdx.x, lane = t&15, rg = t>>4;
  int head = blockIdx.x >> 3, tile = blockIdx.x & 7;
  int r0t = tile*64;
  int r0 = r0t + rg*4;
  int c0 = lane*8;
  const float* W = (head==0) ? Wm : (head==1) ? Ws : Wp;
  const float* D = (head==0) ? Dm : (head==1) ? Ds : Dp;

  float acc[4][8];
  #pragma unroll
  for(int r=0;r<4;r++)
    #pragma unroll
    for(int i=0;i<8;i++) acc[r][i]=0.f;

  for(int kc=0; kc<4; kc++){
    __syncthreads();
    const float4* ws = (const float4*)(W + kc*96*128);
    float4* wd = (float4*)Wbuf;
    #pragma unroll
    for(int i=0;i<12;i++) wd[i*256+t] = ws[i*256+t];
    __syncthreads();
    const float* Ab = agg2 + (long)r0*KDIM + kc*96;
    #pragma unroll 2
    for(int k4=0;k4<96;k4+=4){
      float4 a0 = *(const float4*)(Ab + 0*KDIM + k4);
      float4 a1 = *(const float4*)(Ab + 1*KDIM + k4);
      float4 a2 = *(const float4*)(Ab + 2*KDIM + k4);
      float4 a3 = *(const float4*)(Ab + 3*KDIM + k4);
      #pragma unroll
      for(int kk=0;kk<4;kk++){
        float av0=getc(a0,kk), av1=getc(a1,kk), av2=getc(a2,kk), av3=getc(a3,kk);
        const float* wr = Wbuf + (k4+kk)*128 + c0;
        float4 w0 = *(const float4*)wr;
        float4 w1 = *(const float4*)(wr+4);
        acc[0][0]+=av0*w0.x; acc[0][1]+=av0*w0.y; acc[0][2]+=av0*w0.z; acc[0][3]+=av0*w0.w;
        acc[0][4]+=av0*w1.x; acc[0][5]+=av0*w1.y; acc[0][6]+=av0*w1.z; acc[0][7]+=av0*w1.w;
        acc[1][0]+=av1*w0.x; acc[1][1]+=av1*w0.y; acc[1][2]+=av1*w0.z; acc[1][3]+=av1*w0.w;
        acc[1][4]+=av1*w1.x; acc[1][5]+=av1*w1.y; acc[1][6]+=av1*w1.z; acc[1][7]+=av1*w1.w;
        acc[2][0]+=av2*w0.x; acc[2][1]+=av2*w0.y; acc[2][2]+=av2*w0.z; acc[2][3]+=av2*w0.w;
        acc[2][4]+=av2*w1.x; acc[2][5]+=av2*w1.y; acc[2][6]+=av2*w1.z; acc[2][7]+=av2*w1.w;
        acc[3][0]+=av3*w0.x; acc[3][1]+=av3*w0.y; acc[3][2]+=av3*w0.z; acc[3][3]+=av3*w0.w;
        acc[3][4]+=av3*w1.x; acc[3][5]+=av3*w1.y; acc[3][6]+=av3*w1.z; acc[3][7]+=av3*w1.w;
      }
    }
  }
  // sigmoid -> hb
  #pragma unroll
  for(int r=0;r<4;r++){
    float* hp = hb + (rg*4+r)*133 + c0;
    #pragma unroll
    for(int i=0;i<8;i++) hp[i] = sigf(acc[r][i]);
  }
  __syncthreads();
  // stage D (128x64) into Wbuf
  {
    const float4* ds = (const float4*)D;
    float4* dd = (float4*)Wbuf;
    #pragma unroll
    for(int i=0;i<8;i++) dd[i*256+t] = ds[i*256+t];
  }
  __syncthreads();
  // projection: thread = 4 rows x 4 cols
  {
    int cd = lane*4;
    float a2[4][4];
    #pragma unroll
    for(int r=0;r<4;r++)
      #pragma unroll
      for(int i=0;i<4;i++) a2[r][i]=0.f;
    #pragma unroll 4
    for(int k=0;k<FDIM;k++){
      float4 d = *(const float4*)(Wbuf + k*64 + cd);
      #pragma unroll
      for(int r=0;r<4;r++){
        float hv = hb[(rg*4+r)*133 + k];
        a2[r][0]+=hv*d.x; a2[r][1]+=hv*d.y; a2[r][2]+=hv*d.z; a2[r][3]+=hv*d.w;
      }
    }
    #pragma unroll
    for(int r=0;r<4;r++){
      int row = r0 + r;
      int side = row >> 8, b = row & 255;
      float* op = out + ((long)(side*3+head)*256 + b)*64 + cd;
      *(float4*)op = make_float4(a2[r][0],a2[r][1],a2[r][2],a2[r][3]);
    }
  }
}

// ---------------- launch ----------------
extern "C" void kernel_launch(void* const* d_in, const int* in_sizes, int n_in,
                              void* d_out, int out_size, void* d_ws, size_t ws_size,
                              hipStream_t stream) {
  const int*   nodes1  = (const int*)d_in[0];
  const int*   nodes2  = (const int*)d_in[1];
  const int*   nout    = (const int*)d_in[2];
  const int*   nin     = (const int*)d_in[3];
  const float* feat    = (const float*)d_in[4];
  const float* W_in    = (const float*)d_in[5];
  const float* W_mean  = (const float*)d_in[6];
  const float* W_std   = (const float*)d_in[7];
  const float* W_pi    = (const float*)d_in[8];
  const float* Wd_mean = (const float*)d_in[11];
  const float* Wd_std  = (const float*)d_in[12];
  const float* Wd_pi   = (const float*)d_in[13];
  float* out = (float*)d_out;

  // workspace: s_hop1 | h[26112][128] | agg2[512][384] | aggChunk
  int*   s_hop1 = (int*)d_ws;                          // 25600 ints
  float* h      = (float*)(s_hop1 + 25600);            // 26112*128
  float* agg2   = h + (size_t)NROWS*FDIM;              // 512*384
  float* aggC   = agg2 + 512*KDIM;

  // chunk count: smallest that fits ws (constant per session -> graph-safe)
  size_t fixedB = 25600*4 + (size_t)NROWS*FDIM*4 + 512*KDIM*4;
  const int ncOpt[5] = {1,2,4,8,24};                   // all divide 408 blocks
  int nc = 24;
  for(int i=0;i<5;i++){
    size_t need = fixedB + ((size_t)NROWS/ncOpt[i])*KDIM*4;
    if(need <= ws_size){ nc = ncOpt[i]; break; }
  }
  int chunkRows = NROWS / nc;

  ColsBoth cb;
  compute_cols(cb);

  sample1_kernel<<<(2*256*50 + 255)/256, 256, 0, stream>>>(nodes1, nodes2, nout, nin, s_hop1, cb);
  for(int c=0;c<nc;c++){
    int base = c*chunkRows;
    gather_kernel<<<chunkRows/8, 256, 0, stream>>>(feat, nodes1, nodes2, s_hop1,
                                                   nout, nin, aggC, base, cb);
    gemm_sig_kernel<<<chunkRows/64, 256, 0, stream>>>(aggC, W_in, h + (size_t)base*FDIM);
  }
  // h0 = h[0:512), h1 = h[512:26112)
  agg1_kernel<<<512, 256, 0, stream>>>(h, h + 512*FDIM, agg2);
  head_kernel<<<24, 256, 0, stream>>>(agg2, W_mean, W_std, W_pi, Wd_mean, Wd_std, Wd_pi, out);
}